// Round 2
// baseline (61.042 us; speedup 1.0000x reference)
//
#include <hip/hip_runtime.h>
#include <math.h>

#define BS 16
#define NQ 100
#define NPTS 25
#define VOC 96
#define NC (VOC + 1)       // 97 classes incl. padding
#define MAXLEN 25
#define NGT 32
#define EDIM 300
#define NCOL (BS * NGT)    // 512
#define NDIM (NPTS * 2)    // 50
#define TQ 4               // queries per assemble block (divides NQ)

// ---------------- workspace layout (floats) ----------------
#define WS_GRAM 0                                   // VOC*VOC = 9216
#define WS_LOGP (WS_GRAM + VOC * VOC)               // BS*NQ*VOC = 153600
#define WS_CC (WS_LOGP + BS * NQ * VOC)             // BS*NQ = 1600
#define WS_TGTT (WS_CC + BS * NQ)                   // NDIM*NCOL = 25600

#define GRAM_BLKS VOC              // 96
#define PRED_BLKS (BS * NQ)        // 1600
#define TR_BLKS ((NDIM * NCOL) / 128)  // 200
#define K1_BLKS (GRAM_BLKS + PRED_BLKS + TR_BLKS)

// ---- K1: role-split: gram rows | pred (logp + focal) | tgt-point transpose
__global__ __launch_bounds__(128) void k1_kernel(
        const float* __restrict__ logits1,   // (bq,25,1)
        const float* __restrict__ tlogits,   // (bq,25,97)
        const float* __restrict__ cen,       // (96,300)
        const float* __restrict__ tgt_pts,   // (512,50)
        float* __restrict__ gram, float* __restrict__ logp,
        float* __restrict__ cost_class, float* __restrict__ tgtT) {
    __shared__ float smem[NPTS * NC];        // 2425 floats; reused per role
    int blk = blockIdx.x, tid = threadIdx.x;
    int wave = tid >> 6, lane = tid & 63;

    if (blk < GRAM_BLKS) {
        // ---- gram row v = blk: softmax_c( dot(cen[v],cen[c]) / sqrt(EDIM) )
        float* row = smem;                   // 300
        float* red = smem + 512;             // 128
        for (int k = tid; k < EDIM; k += 128) row[k] = cen[blk * EDIM + k];
        __syncthreads();
        float val = -INFINITY;
        if (tid < VOC) {
            float acc = 0.f;
            const float* c = cen + (size_t)tid * EDIM;
            for (int k = 0; k < EDIM; ++k) acc += row[k] * c[k];
            val = acc * 0.05773502691896258f;   // 1/sqrt(300)
        }
        red[tid] = val;
        __syncthreads();
        for (int s = 64; s > 0; s >>= 1) { if (tid < s) red[tid] = fmaxf(red[tid], red[tid + s]); __syncthreads(); }
        float m = red[0];
        __syncthreads();
        float e = (tid < VOC) ? expf(val - m) : 0.f;
        red[tid] = e;
        __syncthreads();
        for (int s = 64; s > 0; s >>= 1) { if (tid < s) red[tid] += red[tid + s]; __syncthreads(); }
        if (tid < VOC) gram[blk * VOC + tid] = e / red[0];
    } else if (blk < GRAM_BLKS + PRED_BLKS) {
        // ---- pred unit bq: per-point softmax -> mean prob -> logp; focal cost
        int bq = blk - GRAM_BLKS;
        const float* src = tlogits + (size_t)bq * NPTS * NC;
        for (int i = tid; i < NPTS * NC; i += 128) smem[i] = src[i];
        __syncthreads();
        for (int p = wave; p < NPTS; p += 2) {
            float* r = smem + p * NC;
            float x0 = r[lane];
            float x1 = (lane < NC - 64) ? r[64 + lane] : -INFINITY;
            float m = fmaxf(x0, x1);
            for (int o = 32; o > 0; o >>= 1) m = fmaxf(m, __shfl_xor(m, o));
            float e0 = expf(x0 - m);
            float e1 = (lane < NC - 64) ? expf(x1 - m) : 0.f;
            float s = e0 + e1;
            for (int o = 32; o > 0; o >>= 1) s += __shfl_xor(s, o);
            float inv = 1.f / s;
            r[lane] = e0 * inv;                       // store normalized prob
            if (lane < NC - 64) r[64 + lane] = e1 * inv;
        }
        __syncthreads();
        if (tid < VOC) {
            float acc = 0.f;
#pragma unroll
            for (int p = 0; p < NPTS; ++p) acc += smem[p * NC + tid];
            logp[(size_t)bq * VOC + tid] = logf(fmaxf(acc * (1.f / NPTS), 1e-6f));
        }
        if (wave == 0) {
            float sig = 0.f;
            if (lane < NPTS) { float x = logits1[bq * NPTS + lane]; sig = 1.f / (1.f + expf(-x)); }
            for (int o = 32; o > 0; o >>= 1) sig += __shfl_xor(sig, o);
            if (lane == 0) {
                float prob = sig * (1.f / NPTS);
                float negc = 0.75f * prob * prob * (-logf(1.f - prob + 1e-8f));
                float posc = 0.25f * (1.f - prob) * (1.f - prob) * (-logf(prob + 1e-8f));
                cost_class[bq] = posc - negc;
            }
        }
    } else {
        // ---- transpose tgt points (512,50) -> (50,512)
        int g = (blk - GRAM_BLKS - PRED_BLKS) * 128 + tid;   // < 25600 exactly
        int k = g / NCOL;
        int j = g - k * NCOL;
        tgtT[g] = tgt_pts[(size_t)j * NDIM + k];
    }
}

// ---- K2: fused target-stats + assemble. 256 thr, TQ=4 queries/block, 400 blocks.
__global__ __launch_bounds__(256) void k2_kernel(
        const float* __restrict__ pred_pts,  // (1600,50)
        const float* __restrict__ tgtT,      // (50,512)
        const float* __restrict__ gram,      // (96,96)
        const int* __restrict__ texts,       // (16,32,25)
        const float* __restrict__ logp,      // (1600,96)
        const float* __restrict__ cost_class,// (1600,)
        float* __restrict__ out) {           // (1600,512)
    int blk = blockIdx.x, tid = threadIdx.x;
    int bq0 = blk * TQ;
    int b = bq0 / NQ;                        // TQ | NQ so block is single-b
    int wave = tid >> 6, lane = tid & 63;

    __shared__ int   s_tex[NGT * MAXLEN];    // 800
    __shared__ float s_ts[NGT][VOC + 1];     // stride 97 -> conflict-free
    __shared__ float s_ne[NGT];
    __shared__ float s_lp[TQ][VOC];
    __shared__ float s_pp[TQ][NDIM];
    __shared__ float s_cc[TQ];
    __shared__ float s_ct[TQ][NGT];

    for (int i = tid; i < NGT * MAXLEN; i += 256) s_tex[i] = texts[b * NGT * MAXLEN + i];
    for (int i = tid; i < TQ * VOC; i += 256) s_lp[i / VOC][i % VOC] = logp[(size_t)bq0 * VOC + i];
    for (int i = tid; i < TQ * NDIM; i += 256) s_pp[i / NDIM][i % NDIM] = pred_pts[(size_t)bq0 * NDIM + i];
    if (tid < TQ) s_cc[tid] = cost_class[bq0 + tid];
    __syncthreads();

    // ---- per-target soft distribution + entropy (wave w handles g = w+4j)
    for (int j = 0; j < 8; ++j) {
        int g = wave + 4 * j;
        const int* tx = s_tex + g * MAXLEN;
        float a0 = 0.f, a1 = 0.f;
        int len = 0;
#pragma unroll
        for (int l = 0; l < MAXLEN; ++l) {
            int v = tx[l];
            if (v != VOC) {
                ++len;
                a0 += gram[v * VOC + lane];
                if (lane < VOC - 64) a1 += gram[v * VOC + 64 + lane];
            }
        }
        float dinv = 1.f / (float)(len > 0 ? len : 1);
        float t0 = fmaxf(a0 * dinv, 1e-6f);
        float t1 = (lane < VOC - 64) ? fmaxf(a1 * dinv, 1e-6f) : 0.f;
        float s = t0 + t1;
        for (int o = 32; o > 0; o >>= 1) s += __shfl_xor(s, o);
        float inv = 1.f / s;
        float ts0 = t0 * inv, ts1 = t1 * inv;
        float c0 = ts0 * logf(ts0);
        float c1 = (lane < VOC - 64) ? ts1 * logf(ts1) : 0.f;
        float ent = c0 + c1;
        for (int o = 32; o > 0; o >>= 1) ent += __shfl_xor(ent, o);
        s_ts[g][lane] = len ? ts0 : 0.f;
        if (lane < VOC - 64) s_ts[g][64 + lane] = len ? ts1 : 0.f;
        if (lane == 0) s_ne[g] = len ? ent : 100.f;
    }
    __syncthreads();

    // ---- KL: ct[q][g] = max(neg_ent - <logp_q, ts_g>, 0)
    if (tid < TQ * NGT) {
        int q = tid >> 5, g = tid & 31;
        float dot = 0.f;
#pragma unroll
        for (int c = 0; c < VOC; ++c) dot += s_lp[q][c] * s_ts[g][c];
        s_ct[q][g] = fmaxf(s_ne[g] - dot, 0.f);
    }
    __syncthreads();

    // ---- L1 cdist over 50 dims, 2 cols per thread
    float acc[TQ][2];
#pragma unroll
    for (int q = 0; q < TQ; ++q) { acc[q][0] = 0.f; acc[q][1] = 0.f; }
    for (int k = 0; k < NDIM; ++k) {
        float tv0 = tgtT[k * NCOL + tid];
        float tv1 = tgtT[k * NCOL + 256 + tid];
#pragma unroll
        for (int q = 0; q < TQ; ++q) {
            float p = s_pp[q][k];
            acc[q][0] += fabsf(p - tv0);
            acc[q][1] += fabsf(p - tv1);
        }
    }

    // ---- write
    int b0 = tid >> 5, g0 = tid & 31;
    int b1 = (tid + 256) >> 5;
#pragma unroll
    for (int q = 0; q < TQ; ++q) {
        float t0c = (b0 == b) ? s_ct[q][g0] : 0.f;
        float t1c = (b1 == b) ? s_ct[q][g0] : 0.f;   // g index = (col & 31) == tid & 31
        out[(size_t)(bq0 + q) * NCOL + tid] = s_cc[q] + acc[q][0] + t0c;
        out[(size_t)(bq0 + q) * NCOL + 256 + tid] = s_cc[q] + acc[q][1] + t1c;
    }
}

extern "C" void kernel_launch(void* const* d_in, const int* in_sizes, int n_in,
                              void* d_out, int out_size, void* d_ws, size_t ws_size,
                              hipStream_t stream) {
    const float* pred_logits      = (const float*)d_in[0];
    const float* pred_ctrl_points = (const float*)d_in[1];
    const float* pred_text_logits = (const float*)d_in[2];
    const float* tgt_ctrl_points  = (const float*)d_in[3];
    const int*   target_texts     = (const int*)d_in[4];
    const float* centroids        = (const float*)d_in[5];
    float* out = (float*)d_out;
    float* ws = (float*)d_ws;

    float* gram = ws + WS_GRAM;
    float* logp = ws + WS_LOGP;
    float* cc   = ws + WS_CC;
    float* tgtT = ws + WS_TGTT;

    k1_kernel<<<K1_BLKS, 128, 0, stream>>>(pred_logits, pred_text_logits, centroids,
                                           tgt_ctrl_points, gram, logp, cc, tgtT);
    k2_kernel<<<(BS * NQ) / TQ, 256, 0, stream>>>(pred_ctrl_points, tgtT, gram,
                                                  target_texts, logp, cc, out);
}

// Round 3
// 41.819 us; speedup vs baseline: 1.4597x; 1.4597x over previous
//
#include <hip/hip_runtime.h>
#include <math.h>

#define BS 16
#define NQ 100
#define NPTS 25
#define VOC 96
#define NC (VOC + 1)       // 97 classes incl. padding
#define MAXLEN 25
#define NGT 32
#define EDIM 300
#define NCOL (BS * NGT)    // 512
#define NDIM (NPTS * 2)    // 50
#define TQ 4               // queries per assemble block (divides NQ)

// ---------------- workspace layout (floats) ----------------
// gram has an EXTRA zero row at index VOC so gathers are branch-free.
#define WS_GRAM 0                                   // (VOC+1)*VOC = 9312
#define WS_LOGP (WS_GRAM + (VOC + 1) * VOC)         // BS*NQ*VOC = 153600
#define WS_CC (WS_LOGP + BS * NQ * VOC)             // BS*NQ = 1600
#define WS_TGTT (WS_CC + BS * NQ)                   // NDIM*NCOL = 25600

#define GRAM_BLKS VOC              // 96
#define PRED_BLKS (BS * NQ)        // 1600
#define TR_BLKS ((NDIM * NCOL) / 128)  // 200
#define K1_BLKS (GRAM_BLKS + PRED_BLKS + TR_BLKS)

// ---- K1: role-split: gram rows | pred (logp + focal) | tgt-point transpose
__global__ __launch_bounds__(128) void k1_kernel(
        const float* __restrict__ logits1,   // (bq,25,1)
        const float* __restrict__ tlogits,   // (bq,25,97)
        const float* __restrict__ cen,       // (96,300)
        const float* __restrict__ tgt_pts,   // (512,50)
        float* __restrict__ gram, float* __restrict__ logp,
        float* __restrict__ cost_class, float* __restrict__ tgtT) {
    __shared__ float smem[NPTS * NC];        // 2425 floats; reused per role
    int blk = blockIdx.x, tid = threadIdx.x;
    int wave = tid >> 6, lane = tid & 63;

    if (blk < GRAM_BLKS) {
        // ---- gram row v = blk: softmax_c( dot(cen[v],cen[c]) / sqrt(EDIM) )
        float* row = smem;                   // 300
        float* red = smem + 512;             // 128
        for (int k = tid; k < EDIM; k += 128) row[k] = cen[blk * EDIM + k];
        // zero padding row (written once by block 0)
        if (blk == 0 && tid < VOC) gram[(size_t)VOC * VOC + tid] = 0.f;
        __syncthreads();
        float val = -INFINITY;
        if (tid < VOC) {
            float acc = 0.f;
            const float* c = cen + (size_t)tid * EDIM;
            for (int k = 0; k < EDIM; ++k) acc += row[k] * c[k];
            val = acc * 0.05773502691896258f;   // 1/sqrt(300)
        }
        red[tid] = val;
        __syncthreads();
        for (int s = 64; s > 0; s >>= 1) { if (tid < s) red[tid] = fmaxf(red[tid], red[tid + s]); __syncthreads(); }
        float m = red[0];
        __syncthreads();
        float e = (tid < VOC) ? expf(val - m) : 0.f;
        red[tid] = e;
        __syncthreads();
        for (int s = 64; s > 0; s >>= 1) { if (tid < s) red[tid] += red[tid + s]; __syncthreads(); }
        if (tid < VOC) gram[blk * VOC + tid] = e / red[0];
    } else if (blk < GRAM_BLKS + PRED_BLKS) {
        // ---- pred unit bq: per-point softmax -> mean prob -> logp; focal cost
        int bq = blk - GRAM_BLKS;
        const float* src = tlogits + (size_t)bq * NPTS * NC;
        for (int i = tid; i < NPTS * NC; i += 128) smem[i] = src[i];
        __syncthreads();
        for (int p = wave; p < NPTS; p += 2) {
            float* r = smem + p * NC;
            float x0 = r[lane];
            float x1 = (lane < NC - 64) ? r[64 + lane] : -INFINITY;
            float m = fmaxf(x0, x1);
            for (int o = 32; o > 0; o >>= 1) m = fmaxf(m, __shfl_xor(m, o));
            float e0 = expf(x0 - m);
            float e1 = (lane < NC - 64) ? expf(x1 - m) : 0.f;
            float s = e0 + e1;
            for (int o = 32; o > 0; o >>= 1) s += __shfl_xor(s, o);
            float inv = 1.f / s;
            r[lane] = e0 * inv;                       // store normalized prob
            if (lane < NC - 64) r[64 + lane] = e1 * inv;
        }
        __syncthreads();
        if (tid < VOC) {
            float acc = 0.f;
#pragma unroll
            for (int p = 0; p < NPTS; ++p) acc += smem[p * NC + tid];
            logp[(size_t)bq * VOC + tid] = logf(fmaxf(acc * (1.f / NPTS), 1e-6f));
        }
        if (wave == 0) {
            float sig = 0.f;
            if (lane < NPTS) { float x = logits1[bq * NPTS + lane]; sig = 1.f / (1.f + expf(-x)); }
            for (int o = 32; o > 0; o >>= 1) sig += __shfl_xor(sig, o);
            if (lane == 0) {
                float prob = sig * (1.f / NPTS);
                float negc = 0.75f * prob * prob * (-logf(1.f - prob + 1e-8f));
                float posc = 0.25f * (1.f - prob) * (1.f - prob) * (-logf(prob + 1e-8f));
                cost_class[bq] = posc - negc;
            }
        }
    } else {
        // ---- transpose tgt points (512,50) -> (50,512)
        int g = (blk - GRAM_BLKS - PRED_BLKS) * 128 + tid;   // < 25600 exactly
        int k = g / NCOL;
        int j = g - k * NCOL;
        tgtT[g] = tgt_pts[(size_t)j * NDIM + k];
    }
}

// ---- K2: fused target-stats + assemble. 256 thr, TQ=4 queries/block, 400 blocks.
__global__ __launch_bounds__(256) void k2_kernel(
        const float* __restrict__ pred_pts,  // (1600,50)
        const float* __restrict__ tgtT,      // (50,512)
        const float* __restrict__ gram,      // (97,96), row 96 = zeros
        const int* __restrict__ texts,       // (16,32,25)
        const float* __restrict__ logp,      // (1600,96)
        const float* __restrict__ cost_class,// (1600,)
        float* __restrict__ out) {           // (1600,512)
    int blk = blockIdx.x, tid = threadIdx.x;
    int bq0 = blk * TQ;
    int b = bq0 / NQ;                        // TQ | NQ so block is single-b
    int wave = tid >> 6, lane = tid & 63;

    __shared__ int   s_tex[NGT * MAXLEN];    // 800
    __shared__ float s_ts[NGT][VOC + 1];     // stride 97 -> conflict-free
    __shared__ float s_ne[NGT];
    __shared__ float s_lp[TQ][VOC];
    __shared__ float s_pp[TQ][NDIM];
    __shared__ float s_cc[TQ];
    __shared__ float s_ct[TQ][NGT];

    for (int i = tid; i < NGT * MAXLEN; i += 256) s_tex[i] = texts[b * NGT * MAXLEN + i];
    for (int i = tid; i < TQ * VOC; i += 256) s_lp[i / VOC][i % VOC] = logp[(size_t)bq0 * VOC + i];
    for (int i = tid; i < TQ * NDIM; i += 256) s_pp[i / NDIM][i % NDIM] = pred_pts[(size_t)bq0 * NDIM + i];
    if (tid < TQ) s_cc[tid] = cost_class[bq0 + tid];
    __syncthreads();

    // ---- per-target soft distribution + entropy (wave w handles g = w+4j)
    // Branch-free: gram row VOC is all zeros, so padding chars add 0.
    for (int j = 0; j < 8; ++j) {
        int g = wave + 4 * j;
        const int* tx = s_tex + g * MAXLEN;
        float a0 = 0.f, a1 = 0.f;
        int len = 0;
#pragma unroll
        for (int l = 0; l < MAXLEN; ++l) {
            int v = tx[l];                               // wave-uniform broadcast
            len += (v != VOC);
            const float* gr = gram + (size_t)v * VOC;    // row VOC = zeros
            a0 += gr[lane];
            a1 += (lane < VOC - 64) ? gr[64 + lane] : 0.f;
        }
        float dinv = 1.f / (float)(len > 0 ? len : 1);
        float t0 = fmaxf(a0 * dinv, 1e-6f);
        float t1 = (lane < VOC - 64) ? fmaxf(a1 * dinv, 1e-6f) : 0.f;
        float s = t0 + t1;
        for (int o = 32; o > 0; o >>= 1) s += __shfl_xor(s, o);
        float inv = 1.f / s;
        float ts0 = t0 * inv, ts1 = t1 * inv;
        float c0 = ts0 * logf(ts0);
        float c1 = (lane < VOC - 64) ? ts1 * logf(ts1) : 0.f;
        float ent = c0 + c1;
        for (int o = 32; o > 0; o >>= 1) ent += __shfl_xor(ent, o);
        s_ts[g][lane] = len ? ts0 : 0.f;
        if (lane < VOC - 64) s_ts[g][64 + lane] = len ? ts1 : 0.f;
        if (lane == 0) s_ne[g] = len ? ent : 100.f;
    }
    __syncthreads();

    // ---- KL: ct[q][g] = max(neg_ent - <logp_q, ts_g>, 0); 4-way chain break
    if (tid < TQ * NGT) {
        int q = tid >> 5, g = tid & 31;
        float d0 = 0.f, d1 = 0.f, d2 = 0.f, d3 = 0.f;
#pragma unroll
        for (int c = 0; c < VOC; c += 4) {
            d0 += s_lp[q][c]     * s_ts[g][c];
            d1 += s_lp[q][c + 1] * s_ts[g][c + 1];
            d2 += s_lp[q][c + 2] * s_ts[g][c + 2];
            d3 += s_lp[q][c + 3] * s_ts[g][c + 3];
        }
        s_ct[q][g] = fmaxf(s_ne[g] - (d0 + d1 + d2 + d3), 0.f);
    }
    __syncthreads();

    // ---- L1 cdist over 50 dims, 2 cols per thread
    float acc[TQ][2];
#pragma unroll
    for (int q = 0; q < TQ; ++q) { acc[q][0] = 0.f; acc[q][1] = 0.f; }
#pragma unroll 10
    for (int k = 0; k < NDIM; ++k) {
        float tv0 = tgtT[k * NCOL + tid];
        float tv1 = tgtT[k * NCOL + 256 + tid];
#pragma unroll
        for (int q = 0; q < TQ; ++q) {
            float p = s_pp[q][k];
            acc[q][0] += fabsf(p - tv0);
            acc[q][1] += fabsf(p - tv1);
        }
    }

    // ---- write
    int b0 = tid >> 5, g0 = tid & 31;
    int b1 = (tid + 256) >> 5;
#pragma unroll
    for (int q = 0; q < TQ; ++q) {
        float t0c = (b0 == b) ? s_ct[q][g0] : 0.f;
        float t1c = (b1 == b) ? s_ct[q][g0] : 0.f;
        out[(size_t)(bq0 + q) * NCOL + tid] = s_cc[q] + acc[q][0] + t0c;
        out[(size_t)(bq0 + q) * NCOL + 256 + tid] = s_cc[q] + acc[q][1] + t1c;
    }
}

extern "C" void kernel_launch(void* const* d_in, const int* in_sizes, int n_in,
                              void* d_out, int out_size, void* d_ws, size_t ws_size,
                              hipStream_t stream) {
    const float* pred_logits      = (const float*)d_in[0];
    const float* pred_ctrl_points = (const float*)d_in[1];
    const float* pred_text_logits = (const float*)d_in[2];
    const float* tgt_ctrl_points  = (const float*)d_in[3];
    const int*   target_texts     = (const int*)d_in[4];
    const float* centroids        = (const float*)d_in[5];
    float* out = (float*)d_out;
    float* ws = (float*)d_ws;

    float* gram = ws + WS_GRAM;
    float* logp = ws + WS_LOGP;
    float* cc   = ws + WS_CC;
    float* tgtT = ws + WS_TGTT;

    k1_kernel<<<K1_BLKS, 128, 0, stream>>>(pred_logits, pred_text_logits, centroids,
                                           tgt_ctrl_points, gram, logp, cc, tgtT);
    k2_kernel<<<(BS * NQ) / TQ, 256, 0, stream>>>(pred_ctrl_points, tgtT, gram,
                                                  target_texts, logp, cc, out);
}